// Round 3
// baseline (1430.842 us; speedup 1.0000x reference)
//
#include <hip/hip_runtime.h>
#include <hip/hip_bf16.h>

#define T_DIM 4096
#define H_DIM 2048
#define I_DIM 2048
#define E_NUM 16

#define BM 128
#define BN 128
#define BK 32

// padded-rows cap: sum(cnt)=8192, each expert pads +<=127 -> <=10224; use 10240
#define MAX_ROWS 10240

using frag_ab = __attribute__((ext_vector_type(8))) short;   // 8 bf16 in 4 VGPRs
using frag_cd = __attribute__((ext_vector_type(4))) float;   // 4 fp32 acc
using ushort8 = __attribute__((ext_vector_type(8))) unsigned short;

__device__ __forceinline__ unsigned short f2bf(float f) {
    unsigned int u = __float_as_uint(f);
    u += 0x7fff + ((u >> 16) & 1);      // RNE
    return (unsigned short)(u >> 16);
}
__device__ __forceinline__ float bf2f(unsigned short s) {
    return __uint_as_float(((unsigned int)s) << 16);
}

// async global->LDS, 16B per lane; LDS dest is wave-uniform base + lane*16
__device__ __forceinline__ void gld16(const void* g, void* l) {
    __builtin_amdgcn_global_load_lds(
        (const __attribute__((address_space(1))) unsigned int*)g,
        (__attribute__((address_space(3))) unsigned int*)l, 16, 0, 0);
}

// ---------------- routing: logits -> top2 -> expert lists ----------------
__global__ void routing_kernel(const float* __restrict__ x,
                               const float* __restrict__ gw,
                               int* __restrict__ cnt,
                               int* __restrict__ tok_list,
                               float* __restrict__ tok_w) {
    const int wave = threadIdx.x >> 6;
    const int lane = threadIdx.x & 63;
    const int t = blockIdx.x * 4 + wave;
    if (t >= T_DIM) return;

    float acc[E_NUM];
#pragma unroll
    for (int e = 0; e < E_NUM; ++e) acc[e] = 0.f;
    const float* xr = x + (size_t)t * H_DIM;
    for (int j = lane; j < H_DIM; j += 64) {
        float xv = xr[j];
#pragma unroll
        for (int e = 0; e < E_NUM; ++e)
            acc[e] = fmaf(xv, gw[e * H_DIM + j], acc[e]);
    }
#pragma unroll
    for (int e = 0; e < E_NUM; ++e) {
        float v = acc[e];
#pragma unroll
        for (int off = 32; off > 0; off >>= 1) v += __shfl_xor(v, off);
        acc[e] = v;
    }
    if (lane == 0) {
        int b1 = 0; float l1 = acc[0];
#pragma unroll
        for (int e = 1; e < E_NUM; ++e)
            if (acc[e] > l1) { l1 = acc[e]; b1 = e; }
        int b2 = -1; float l2 = -1e30f;
#pragma unroll
        for (int e = 0; e < E_NUM; ++e)
            if (e != b1 && acc[e] > l2) { l2 = acc[e]; b2 = e; }
        // softmax Z cancels in top-2 renorm: w1 = e^l1/(e^l1+e^l2)
        float w1 = 1.f / (1.f + __expf(l2 - l1));
        float w2 = 1.f - w1;
        int p1 = atomicAdd(&cnt[b1], 1);
        tok_list[b1 * T_DIM + p1] = t; tok_w[b1 * T_DIM + p1] = w1;
        int p2 = atomicAdd(&cnt[b2], 1);
        tok_list[b2 * T_DIM + p2] = t; tok_w[b2 * T_DIM + p2] = w2;
    }
}

// ---------------- scan: padded bases ----------------
__global__ void scan_kernel(const int* __restrict__ cnt, int* __restrict__ base,
                            int* __restrict__ npad, int* __restrict__ total) {
    int acc = 0;
    for (int e = 0; e < E_NUM; ++e) {
        base[e] = acc;
        int p = (cnt[e] + BM - 1) & ~(BM - 1);
        npad[e] = p;
        acc += p;
    }
    *total = acc;
}

// ---------------- fp32 -> bf16 bulk convert (memory-bound) ----------------
__global__ void __launch_bounds__(256) cvt_kernel(const float* __restrict__ s,
                                                  unsigned short* __restrict__ d,
                                                  size_t n8) {
    const size_t stride = (size_t)gridDim.x * 256;
    for (size_t i = (size_t)blockIdx.x * 256 + threadIdx.x; i < n8; i += stride) {
        const float4* sp = (const float4*)(s + i * 8);
        float4 a = sp[0], b = sp[1];
        ushort8 o;
        o[0] = f2bf(a.x); o[1] = f2bf(a.y); o[2] = f2bf(a.z); o[3] = f2bf(a.w);
        o[4] = f2bf(b.x); o[5] = f2bf(b.y); o[6] = f2bf(b.z); o[7] = f2bf(b.w);
        *(ushort8*)(d + i * 8) = o;
    }
}

// ---------------- GEMM1 (bf16 inputs): gate_up = Xe @ W13^T, gather rows ----------------
__global__ void __launch_bounds__(256) gemm1_bf_kernel(
    const unsigned short* __restrict__ xb, const unsigned short* __restrict__ wb,
    const int* __restrict__ tok_list,
    const int* __restrict__ cnt, const int* __restrict__ base,
    const int* __restrict__ npad, unsigned short* __restrict__ gu)
{
    const int e = blockIdx.z;
    const int mt = blockIdx.y;
    if (mt * BM >= npad[e]) return;
    const int nt = blockIdx.x;

    __shared__ unsigned short As[BM * BK];
    __shared__ unsigned short Bs[BN * BK];

    const int tid = threadIdx.x;
    const int lane = tid & 63;
    const int wv = tid >> 6;
    const int wm = (wv >> 1) * 64;
    const int wn = (wv & 1) * 64;
    const int quad = lane >> 4;
    const int l16 = lane & 15;

    const int* tl = tok_list + e * T_DIM + mt * BM;
    const int lim = cnt[e] - mt * BM - 1;    // >=0 guaranteed (mt*BM < npad)

    // staging geometry: lane covers row (wv*16 + lane/4), cols (lane&3)*8 .. +8
    const int srow = wv * 16 + (lane >> 2);  // 0..63
    const int scol = (lane & 3) * 8;

    const int r0 = srow      <= lim ? srow      : lim;
    const int r1 = srow + 64 <= lim ? srow + 64 : lim;
    const unsigned short* ag0 = xb + (size_t)tl[r0] * H_DIM + scol;
    const unsigned short* ag1 = xb + (size_t)tl[r1] * H_DIM + scol;
    const unsigned short* bg0 = wb + (size_t)e * (2 * I_DIM) * H_DIM
                                   + (size_t)(nt * BN + srow) * H_DIM + scol;
    const unsigned short* bg1 = bg0 + (size_t)64 * H_DIM;

    unsigned short* al0 = &As[wv * 512];
    unsigned short* al1 = &As[2048 + wv * 512];
    unsigned short* bl0 = &Bs[wv * 512];
    unsigned short* bl1 = &Bs[2048 + wv * 512];

    frag_cd acc[4][4];
#pragma unroll
    for (int i = 0; i < 4; ++i)
#pragma unroll
        for (int j = 0; j < 4; ++j)
            acc[i][j] = (frag_cd){0.f, 0.f, 0.f, 0.f};

    for (int k0 = 0; k0 < H_DIM; k0 += BK) {
        gld16(ag0 + k0, al0);
        gld16(ag1 + k0, al1);
        gld16(bg0 + k0, bl0);
        gld16(bg1 + k0, bl1);
        __syncthreads();               // compiler drains vmcnt(0) before barrier
        frag_ab af[4], bf[4];
#pragma unroll
        for (int i = 0; i < 4; ++i) {
            af[i] = *(const frag_ab*)(&As[(wm + i * 16 + l16) * BK + quad * 8]);
            bf[i] = *(const frag_ab*)(&Bs[(wn + i * 16 + l16) * BK + quad * 8]);
        }
#pragma unroll
        for (int i = 0; i < 4; ++i)
#pragma unroll
            for (int j = 0; j < 4; ++j)
                acc[i][j] = __builtin_amdgcn_mfma_f32_16x16x32_bf16(
                    af[i], bf[j], acc[i][j], 0, 0, 0);
        __syncthreads();
    }

    const size_t gbase = (size_t)(base[e] + mt * BM);
#pragma unroll
    for (int i = 0; i < 4; ++i) {
#pragma unroll
        for (int r = 0; r < 4; ++r) {
            int row = wm + i * 16 + quad * 4 + r;
            unsigned short* gr = gu + (gbase + row) * (size_t)(2 * I_DIM) + nt * BN + wn;
#pragma unroll
            for (int j = 0; j < 4; ++j)
                gr[j * 16 + l16] = f2bf(acc[i][j][r]);
        }
    }
}

// ---------------- SiLU: h = silu(g)*u, in-place into gate half ----------------
__global__ void silu_kernel(unsigned short* __restrict__ gu,
                            const int* __restrict__ total) {
    const int tot = *total;
    size_t idx = ((size_t)blockIdx.x * 256 + threadIdx.x) * 4;
    if (idx >= (size_t)tot * I_DIM) return;
    size_t row = idx >> 11;             // / 2048
    int col = (int)(idx & (I_DIM - 1));
    unsigned short* gp = gu + row * (size_t)(2 * I_DIM) + col;
    ushort4 gv = *(const ushort4*)gp;
    ushort4 uv = *(const ushort4*)(gp + I_DIM);
    float g0 = bf2f(gv.x), g1 = bf2f(gv.y), g2 = bf2f(gv.z), g3 = bf2f(gv.w);
    float u0 = bf2f(uv.x), u1 = bf2f(uv.y), u2 = bf2f(uv.z), u3 = bf2f(uv.w);
    float h0 = g0 / (1.f + __expf(-g0)) * u0;
    float h1 = g1 / (1.f + __expf(-g1)) * u1;
    float h2 = g2 / (1.f + __expf(-g2)) * u2;
    float h3 = g3 / (1.f + __expf(-g3)) * u3;
    *(ushort4*)gp = make_ushort4(f2bf(h0), f2bf(h1), f2bf(h2), f2bf(h3));
}

// ---------------- GEMM2 (bf16 inputs): y = H @ W2^T, scatter-add coef*y ----------------
__global__ void __launch_bounds__(256) gemm2_bf_kernel(
    const unsigned short* __restrict__ gu, const unsigned short* __restrict__ w2b,
    const int* __restrict__ tok_list, const float* __restrict__ tok_w,
    const int* __restrict__ cnt, const int* __restrict__ base,
    const int* __restrict__ npad, float* __restrict__ out)
{
    const int e = blockIdx.z;
    const int mt = blockIdx.y;
    if (mt * BM >= npad[e]) return;
    const int nt = blockIdx.x;

    __shared__ unsigned short As[BM * BK];
    __shared__ unsigned short Bs[BN * BK];
    __shared__ int s_tok[BM];
    __shared__ float s_tw[BM];

    const int tid = threadIdx.x;
    const int lane = tid & 63;
    const int wv = tid >> 6;
    const int wm = (wv >> 1) * 64;
    const int wn = (wv & 1) * 64;
    const int quad = lane >> 4;
    const int l16 = lane & 15;

    const int ne = cnt[e];
    if (tid < BM) {
        int g = mt * BM + tid;
        bool v = g < ne;
        s_tok[tid] = v ? tok_list[e * T_DIM + g] : -1;
        s_tw[tid]  = v ? tok_w[e * T_DIM + g] : 0.f;
    }

    const size_t abase = (size_t)(base[e] + mt * BM);
    const int srow = wv * 16 + (lane >> 2);
    const int scol = (lane & 3) * 8;

    const unsigned short* ag0 = gu + (abase + srow) * (size_t)(2 * I_DIM) + scol;
    const unsigned short* ag1 = ag0 + (size_t)64 * (2 * I_DIM);
    const unsigned short* bg0 = w2b + (size_t)e * H_DIM * I_DIM
                                    + (size_t)(nt * BN + srow) * I_DIM + scol;
    const unsigned short* bg1 = bg0 + (size_t)64 * I_DIM;

    unsigned short* al0 = &As[wv * 512];
    unsigned short* al1 = &As[2048 + wv * 512];
    unsigned short* bl0 = &Bs[wv * 512];
    unsigned short* bl1 = &Bs[2048 + wv * 512];

    frag_cd acc[4][4];
#pragma unroll
    for (int i = 0; i < 4; ++i)
#pragma unroll
        for (int j = 0; j < 4; ++j)
            acc[i][j] = (frag_cd){0.f, 0.f, 0.f, 0.f};

    for (int k0 = 0; k0 < I_DIM; k0 += BK) {
        gld16(ag0 + k0, al0);
        gld16(ag1 + k0, al1);
        gld16(bg0 + k0, bl0);
        gld16(bg1 + k0, bl1);
        __syncthreads();
        frag_ab af[4], bf[4];
#pragma unroll
        for (int i = 0; i < 4; ++i) {
            af[i] = *(const frag_ab*)(&As[(wm + i * 16 + l16) * BK + quad * 8]);
            bf[i] = *(const frag_ab*)(&Bs[(wn + i * 16 + l16) * BK + quad * 8]);
        }
#pragma unroll
        for (int i = 0; i < 4; ++i)
#pragma unroll
            for (int j = 0; j < 4; ++j)
                acc[i][j] = __builtin_amdgcn_mfma_f32_16x16x32_bf16(
                    af[i], bf[j], acc[i][j], 0, 0, 0);
        __syncthreads();
    }

#pragma unroll
    for (int i = 0; i < 4; ++i) {
#pragma unroll
        for (int r = 0; r < 4; ++r) {
            int row = wm + i * 16 + quad * 4 + r;
            int tok = s_tok[row];
            if (tok < 0) continue;
            float coef = s_tw[row];
            float* orow = out + (size_t)tok * H_DIM + nt * BN + wn;
#pragma unroll
            for (int j = 0; j < 4; ++j)
                atomicAdd(&orow[j * 16 + l16], coef * acc[i][j][r]);
        }
    }
}

// ================= fallback path (fp32 weights, convert in-loop) =================
__global__ void __launch_bounds__(256) gemm1_kernel(
    const float* __restrict__ x, const float* __restrict__ ws,
    const int* __restrict__ tok_list,
    const int* __restrict__ cnt, const int* __restrict__ base,
    const int* __restrict__ npad, unsigned short* __restrict__ gu)
{
    const int e = blockIdx.z;
    const int mt = blockIdx.y;
    if (mt * BM >= npad[e]) return;
    const int nt = blockIdx.x;

    __shared__ unsigned short As[BM * BK];
    __shared__ unsigned short Bs[BN * BK];

    const int tid = threadIdx.x;
    const int lane = tid & 63;
    const int wv = tid >> 6;
    const int wm = (wv >> 1) * 64;
    const int wn = (wv & 1) * 64;
    const int quad = lane >> 4;
    const int l16 = lane & 15;

    const int ne = cnt[e];
    const int* tl = tok_list + e * T_DIM + mt * BM;
    const int lim = ne - mt * BM - 1;

    const int ar = tid >> 3;
    const int ac = (tid & 7) * 4;

    const float* xb[4];
#pragma unroll
    for (int it = 0; it < 4; ++it) {
        int r = ar + 32 * it;
        int rr = r < lim ? r : lim;
        xb[it] = x + (size_t)tl[rr] * H_DIM + ac;
    }
    const float* w13 = ws + (size_t)e * (2 * I_DIM) * H_DIM
                          + (size_t)(nt * BN) * H_DIM + ac;

    frag_cd acc[4][4];
#pragma unroll
    for (int i = 0; i < 4; ++i)
#pragma unroll
        for (int j = 0; j < 4; ++j)
            acc[i][j] = (frag_cd){0.f, 0.f, 0.f, 0.f};

    for (int k0 = 0; k0 < H_DIM; k0 += BK) {
#pragma unroll
        for (int it = 0; it < 4; ++it) {
            int r = ar + 32 * it;
            float4 v = *(const float4*)(xb[it] + k0);
            *(ushort4*)(&As[r * BK + ac]) =
                make_ushort4(f2bf(v.x), f2bf(v.y), f2bf(v.z), f2bf(v.w));
            float4 w = *(const float4*)(w13 + (size_t)r * H_DIM + k0);
            *(ushort4*)(&Bs[r * BK + ac]) =
                make_ushort4(f2bf(w.x), f2bf(w.y), f2bf(w.z), f2bf(w.w));
        }
        __syncthreads();
        frag_ab af[4], bf[4];
#pragma unroll
        for (int i = 0; i < 4; ++i) {
            af[i] = *(const frag_ab*)(&As[(wm + i * 16 + l16) * BK + quad * 8]);
            bf[i] = *(const frag_ab*)(&Bs[(wn + i * 16 + l16) * BK + quad * 8]);
        }
#pragma unroll
        for (int i = 0; i < 4; ++i)
#pragma unroll
            for (int j = 0; j < 4; ++j)
                acc[i][j] = __builtin_amdgcn_mfma_f32_16x16x32_bf16(
                    af[i], bf[j], acc[i][j], 0, 0, 0);
        __syncthreads();
    }

    const size_t gbase = (size_t)(base[e] + mt * BM);
#pragma unroll
    for (int i = 0; i < 4; ++i) {
#pragma unroll
        for (int r = 0; r < 4; ++r) {
            int row = wm + i * 16 + quad * 4 + r;
            unsigned short* gr = gu + (gbase + row) * (size_t)(2 * I_DIM) + nt * BN + wn;
#pragma unroll
            for (int j = 0; j < 4; ++j)
                gr[j * 16 + l16] = f2bf(acc[i][j][r]);
        }
    }
}

__global__ void __launch_bounds__(256) gemm2_kernel(
    const unsigned short* __restrict__ gu, const float* __restrict__ w2s,
    const int* __restrict__ tok_list, const float* __restrict__ tok_w,
    const int* __restrict__ cnt, const int* __restrict__ base,
    const int* __restrict__ npad, float* __restrict__ out)
{
    const int e = blockIdx.z;
    const int mt = blockIdx.y;
    if (mt * BM >= npad[e]) return;
    const int nt = blockIdx.x;

    __shared__ unsigned short As[BM * BK];
    __shared__ unsigned short Bs[BN * BK];
    __shared__ int s_tok[BM];
    __shared__ float s_tw[BM];

    const int tid = threadIdx.x;
    const int lane = tid & 63;
    const int wv = tid >> 6;
    const int wm = (wv >> 1) * 64;
    const int wn = (wv & 1) * 64;
    const int quad = lane >> 4;
    const int l16 = lane & 15;

    const int ne = cnt[e];
    if (tid < BM) {
        int g = mt * BM + tid;
        bool v = g < ne;
        s_tok[tid] = v ? tok_list[e * T_DIM + g] : -1;
        s_tw[tid]  = v ? tok_w[e * T_DIM + g] : 0.f;
    }

    const size_t abase = (size_t)(base[e] + mt * BM);
    const int ar2 = tid >> 2;
    const int ac2 = (tid & 3) * 8;
    const unsigned short* ab = gu + (abase + ar2) * (size_t)(2 * I_DIM) + ac2;

    const int ar = tid >> 3;
    const int ac = (tid & 7) * 4;
    const float* w2 = w2s + (size_t)e * H_DIM * I_DIM
                          + (size_t)(nt * BN) * I_DIM + ac;

    frag_cd acc[4][4];
#pragma unroll
    for (int i = 0; i < 4; ++i)
#pragma unroll
        for (int j = 0; j < 4; ++j)
            acc[i][j] = (frag_cd){0.f, 0.f, 0.f, 0.f};

    for (int k0 = 0; k0 < I_DIM; k0 += BK) {
        *(uint4*)(&As[ar2 * BK + ac2]) = *(const uint4*)(ab + k0);
        *(uint4*)(&As[(ar2 + 64) * BK + ac2]) =
            *(const uint4*)(ab + (size_t)64 * (2 * I_DIM) + k0);
#pragma unroll
        for (int it = 0; it < 4; ++it) {
            int r = ar + 32 * it;
            float4 w = *(const float4*)(w2 + (size_t)r * I_DIM + k0);
            *(ushort4*)(&Bs[r * BK + ac]) =
                make_ushort4(f2bf(w.x), f2bf(w.y), f2bf(w.z), f2bf(w.w));
        }
        __syncthreads();
        frag_ab af[4], bf[4];
#pragma unroll
        for (int i = 0; i < 4; ++i) {
            af[i] = *(const frag_ab*)(&As[(wm + i * 16 + l16) * BK + quad * 8]);
            bf[i] = *(const frag_ab*)(&Bs[(wn + i * 16 + l16) * BK + quad * 8]);
        }
#pragma unroll
        for (int i = 0; i < 4; ++i)
#pragma unroll
            for (int j = 0; j < 4; ++j)
                acc[i][j] = __builtin_amdgcn_mfma_f32_16x16x32_bf16(
                    af[i], bf[j], acc[i][j], 0, 0, 0);
        __syncthreads();
    }

#pragma unroll
    for (int i = 0; i < 4; ++i) {
#pragma unroll
        for (int r = 0; r < 4; ++r) {
            int row = wm + i * 16 + quad * 4 + r;
            int tok = s_tok[row];
            if (tok < 0) continue;
            float coef = s_tw[row];
            float* orow = out + (size_t)tok * H_DIM + nt * BN + wn;
#pragma unroll
            for (int j = 0; j < 4; ++j)
                atomicAdd(&orow[j * 16 + l16], coef * acc[i][j][r]);
        }
    }
}

extern "C" void kernel_launch(void* const* d_in, const int* in_sizes, int n_in,
                              void* d_out, int out_size, void* d_ws, size_t ws_size,
                              hipStream_t stream) {
    const float* x   = (const float*)d_in[0];
    const float* gw  = (const float*)d_in[1];
    const float* ws  = (const float*)d_in[2];
    const float* w2s = (const float*)d_in[3];
    float* out = (float*)d_out;

    char* wsp = (char*)d_ws;
    int* cnt   = (int*)(wsp + 0);
    int* basep = (int*)(wsp + 64);
    int* npad  = (int*)(wsp + 128);
    int* total = (int*)(wsp + 192);

    const size_t MB = (size_t)1 << 20;
    // fast path layout:
    //   [1MB,1.5MB) tok_list  [1.5MB,2MB) tok_w
    //   [2MB,18MB) x_bf  [18MB,98MB) gu  [98MB,354MB) ws_bf  [354MB,482MB) w2_bf
    const size_t NEED = 482 * MB;

    hipMemsetAsync(cnt, 0, 64, stream);
    hipMemsetAsync(d_out, 0, (size_t)T_DIM * H_DIM * sizeof(float), stream);

    if (ws_size >= NEED) {
        int*   tok_list = (int*)(wsp + 1 * MB);
        float* tok_w    = (float*)(wsp + 1 * MB + 512 * 1024);
        unsigned short* x_bf  = (unsigned short*)(wsp + 2 * MB);
        unsigned short* gu    = (unsigned short*)(wsp + 18 * MB);
        unsigned short* ws_bf = (unsigned short*)(wsp + 98 * MB);
        unsigned short* w2_bf = (unsigned short*)(wsp + 354 * MB);

        cvt_kernel<<<4096, 256, 0, stream>>>(x, x_bf, (size_t)T_DIM * H_DIM / 8);
        cvt_kernel<<<4096, 256, 0, stream>>>(ws, ws_bf,
            (size_t)E_NUM * 2 * I_DIM * H_DIM / 8);
        cvt_kernel<<<4096, 256, 0, stream>>>(w2s, w2_bf,
            (size_t)E_NUM * H_DIM * I_DIM / 8);

        routing_kernel<<<T_DIM / 4, 256, 0, stream>>>(x, gw, cnt, tok_list, tok_w);
        scan_kernel<<<1, 1, 0, stream>>>(cnt, basep, npad, total);
        gemm1_bf_kernel<<<dim3(2 * I_DIM / BN, T_DIM / BM, E_NUM), 256, 0, stream>>>(
            x_bf, ws_bf, tok_list, cnt, basep, npad, gu);
        silu_kernel<<<(MAX_ROWS * I_DIM / 4) / 256, 256, 0, stream>>>(gu, total);
        gemm2_bf_kernel<<<dim3(H_DIM / BN, T_DIM / BM, E_NUM), 256, 0, stream>>>(
            gu, w2_bf, tok_list, tok_w, cnt, basep, npad, out);
    } else {
        // original (verified) path with original offsets
        int*   tok_list = (int*)(wsp + 256);
        float* tok_w    = (float*)(wsp + 256 + 4 * E_NUM * T_DIM);
        unsigned short* gu = (unsigned short*)(wsp + 512 + 8 * E_NUM * T_DIM);

        routing_kernel<<<T_DIM / 4, 256, 0, stream>>>(x, gw, cnt, tok_list, tok_w);
        scan_kernel<<<1, 1, 0, stream>>>(cnt, basep, npad, total);
        gemm1_kernel<<<dim3(2 * I_DIM / BN, T_DIM / BM, E_NUM), 256, 0, stream>>>(
            x, ws, tok_list, cnt, basep, npad, gu);
        silu_kernel<<<(MAX_ROWS * I_DIM / 4) / 256, 256, 0, stream>>>(gu, total);
        gemm2_kernel<<<dim3(H_DIM / BN, T_DIM / BM, E_NUM), 256, 0, stream>>>(
            gu, w2s, tok_list, tok_w, cnt, basep, npad, out);
    }
}